// Round 6
// baseline (17.703 us; speedup 1.0000x reference)
//
#include <hip/hip_runtime.h>
#include <math.h>

// Local banded attention: B=2, L=2048, H=8, E=D=64, window w=7 (band=15).
// Block = 512 threads (8 waves) = 64 queries of one (b,h).
// Wave-specialized split pipeline with RAW barriers (no vmcnt drain):
//   waves 0-3 stage K (20 chunks), waves 4-7 stage V (20 chunks).
//   K-write -> lgkmcnt(0) -> s_barrier -> QK^T + softmax (V loads still in
//   flight) -> V-write -> lgkmcnt(0) -> s_barrier -> PV.
// K/V live in XOR-swizzled LDS (slot = rl*16 + (c4 ^ (rl&7))) so per-query
// private band reads (8 distinct rows/wave) are bank-even. 8 queries/wave,
// 8 lanes/query, 8 channels/lane. Dot reduce = 3 DPP adds (VALU, no DS).

constexpr int L_DIM = 2048;
constexpr int H_DIM = 8;
constexpr int E_DIM = 64;
constexpr int W = 7;
constexpr int NK = 2 * W + 1;        // 15 band positions per query
constexpr int TQ = 64;               // queries per block
constexpr int HALO = 8;
constexpr int ROWS = TQ + 2 * HALO;  // 80 staged rows

template <int CTRL>
__device__ __forceinline__ float dpp_add(float s) {
  int t = __builtin_amdgcn_mov_dpp(__builtin_bit_cast(int, s), CTRL, 0xF, 0xF, true);
  return s + __builtin_bit_cast(float, t);
}

__global__ __launch_bounds__(512, 2) void local_attn_kernel(
    const float* __restrict__ q,
    const float* __restrict__ k,
    const float* __restrict__ v,
    float* __restrict__ out) {
  __shared__ float ks[ROWS * E_DIM];  // 20 KB
  __shared__ float vs[ROWS * E_DIM];  // 20 KB

  // XCD-aware swizzle (grid = 512, divisible by 8)
  const int cpx = gridDim.x >> 3;
  const int bid = (blockIdx.x & 7) * cpx + (blockIdx.x >> 3);

  const int tile = bid & (L_DIM / TQ - 1);  // 32 tiles per (b,h)
  const int bh = bid >> 5;
  const int h = bh & (H_DIM - 1);
  const int b = bh >> 3;
  const int l0 = tile * TQ;

  const int tid = threadIdx.x;
  const int wv = tid >> 6;     // wave [0,8)
  const int lane = tid & 63;
  const int qsub = lane >> 3;  // query within wave [0,8)
  const int c = lane & 7;      // channel group [0,8)

  const size_t bhb = (size_t)b * L_DIM * H_DIM + h;

  // ---- staging: waves 0-3 own K chunks, waves 4-7 own V chunks ----
  // chunk cc = 4 rows x 64 floats = one float4 per lane;
  // lane: row cc*4 + (lane>>4), 16B col group (lane&15).
  const int rsub = lane >> 4;
  const int c4 = lane & 15;
  const bool isK = (wv < 4);
  const int cbase = (isK ? wv : (wv - 4)) * 5;  // 5 chunks per wave
  const float* mat = isK ? k : v;

  float4 stg[5];
  int slot_s[5];
#pragma unroll
  for (int t = 0; t < 5; ++t) {
    const int rl = (cbase + t) * 4 + rsub;  // LDS row 0..79
    int rg = l0 - HALO + rl;
    rg = rg < 0 ? 0 : (rg > L_DIM - 1 ? L_DIM - 1 : rg);
    slot_s[t] = rl * 16 + (c4 ^ (rl & 7));
    stg[t] = *(const float4*)(mat + ((bhb + (size_t)rg * H_DIM) << 6) + c4 * 4);
  }

  // Q -> regs (overlaps staging latency)
  const int l0w = l0 + wv * 8;
  const int l = l0w + qsub;
  const float* qp = q + ((bhb + (size_t)l * H_DIM) << 6) + c * 8;
  float4 q0 = *(const float4*)qp;
  float4 q1 = *(const float4*)(qp + 4);

  // ---- K waves write LDS (compiler waits K loads only), barrier 1 ----
  if (isK) {
#pragma unroll
    for (int t = 0; t < 5; ++t) *(float4*)&ks[slot_s[t] * 4] = stg[t];
  }
  asm volatile("s_waitcnt lgkmcnt(0)" ::: "memory");
  __builtin_amdgcn_s_barrier();
  __builtin_amdgcn_sched_barrier(0);  // keep ds_reads below the barrier

  const float scale = 0.125f;  // 1/sqrt(64)
  q0.x *= scale; q0.y *= scale; q0.z *= scale; q0.w *= scale;
  q1.x *= scale; q1.y *= scale; q1.z *= scale; q1.w *= scale;

  // ---- scores: each query group walks its own 15-key band ----
  // LDS row for band pos j: rl = wv*8 + 1 + qsub + j (in [1,78])
  const int base_rl = wv * 8 + 1 + qsub;
  float sc[NK];
#pragma unroll
  for (int j = 0; j < NK; ++j) {
    const int rl = base_rl + j;
    const int s8 = rl & 7;
    const float4 k0 = *(const float4*)&ks[(rl * 16 + ((2 * c) ^ s8)) * 4];
    const float4 k1 = *(const float4*)&ks[(rl * 16 + ((2 * c + 1) ^ s8)) * 4];
    float s = q0.x * k0.x + q0.y * k0.y + q0.z * k0.z + q0.w * k0.w +
              q1.x * k1.x + q1.y * k1.y + q1.z * k1.z + q1.w * k1.w;
    s = dpp_add<0xB1>(s);   // xor 1
    s = dpp_add<0x4E>(s);   // xor 2
    s = dpp_add<0x141>(s);  // 8-lane half-row mirror
    const int kk = l0w + qsub - W + j;
    sc[j] = ((unsigned)kk < (unsigned)L_DIM) ? s : -INFINITY;
  }

  // ---- softmax over 15 band scores ----
  float mx = sc[0];
#pragma unroll
  for (int j = 1; j < NK; ++j) mx = fmaxf(mx, sc[j]);
  float den = 0.0f;
#pragma unroll
  for (int j = 0; j < NK; ++j) {
    sc[j] = __expf(sc[j] - mx);
    den += sc[j];
  }
  const float inv = __builtin_amdgcn_rcpf(den);

  // ---- V waves write LDS (V loads landed during QK phase), barrier 2 ----
  __builtin_amdgcn_sched_barrier(0);  // don't let V-writes float up into QK
  if (!isK) {
#pragma unroll
    for (int t = 0; t < 5; ++t) *(float4*)&vs[slot_s[t] * 4] = stg[t];
  }
  asm volatile("s_waitcnt lgkmcnt(0)" ::: "memory");
  __builtin_amdgcn_s_barrier();
  __builtin_amdgcn_sched_barrier(0);

  // ---- PV: private-row walk over V ----
  float4 a0 = {0.f, 0.f, 0.f, 0.f};
  float4 a1 = {0.f, 0.f, 0.f, 0.f};
#pragma unroll
  for (int j = 0; j < NK; ++j) {
    const int rl = base_rl + j;
    const int s8 = rl & 7;
    const float4 v0 = *(const float4*)&vs[(rl * 16 + ((2 * c) ^ s8)) * 4];
    const float4 v1 = *(const float4*)&vs[(rl * 16 + ((2 * c + 1) ^ s8)) * 4];
    const float p = sc[j];
    a0.x += p * v0.x; a0.y += p * v0.y; a0.z += p * v0.z; a0.w += p * v0.w;
    a1.x += p * v1.x; a1.y += p * v1.y; a1.z += p * v1.z; a1.w += p * v1.w;
  }

  float* op = out + ((bhb + (size_t)l * H_DIM) << 6) + c * 8;
  a0.x *= inv; a0.y *= inv; a0.z *= inv; a0.w *= inv;
  a1.x *= inv; a1.y *= inv; a1.z *= inv; a1.w *= inv;
  *(float4*)op = a0;
  *(float4*)(op + 4) = a1;
}

extern "C" void kernel_launch(void* const* d_in, const int* in_sizes, int n_in,
                              void* d_out, int out_size, void* d_ws, size_t ws_size,
                              hipStream_t stream) {
  const float* q = (const float*)d_in[0];
  const float* k = (const float*)d_in[1];
  const float* v = (const float*)d_in[2];
  float* out = (float*)d_out;

  const int B = in_sizes[0] / (L_DIM * H_DIM * E_DIM);  // = 2
  const int blocks = B * H_DIM * (L_DIM / TQ);          // 512

  local_attn_kernel<<<blocks, 512, 0, stream>>>(q, k, v, out);
}

// Round 7
// 13.281 us; speedup vs baseline: 1.3330x; 1.3330x over previous
//
#include <hip/hip_runtime.h>
#include <math.h>

// Local banded attention: B=2, L=2048, H=8, E=D=64, window w=7 (band=15).
// R3 structure (proven 12.27us) with V-staging removed:
//   - K staged to XOR-swizzled LDS (20KB), one __syncthreads.
//   - QK^T: private 15-row band walk per query group from LDS (bank-even).
//   - PV: V read directly from global (L1/L2-hot; each row reused ~15x by
//     cache-local query groups; XCD swizzle keeps reuse on-XCD).
// Wave: 8 queries x 8 lanes x 8 channels. Dot reduce = 3 DPP adds (VALU).

constexpr int L_DIM = 2048;
constexpr int H_DIM = 8;
constexpr int E_DIM = 64;
constexpr int W = 7;
constexpr int NK = 2 * W + 1;        // 15 band positions per query
constexpr int TQ = 64;               // queries per block
constexpr int HALO = 8;
constexpr int ROWS = TQ + 2 * HALO;  // 80 staged K rows

template <int CTRL>
__device__ __forceinline__ float dpp_add(float s) {
  int t = __builtin_amdgcn_mov_dpp(__builtin_bit_cast(int, s), CTRL, 0xF, 0xF, true);
  return s + __builtin_bit_cast(float, t);
}

__global__ __launch_bounds__(512, 4) void local_attn_kernel(
    const float* __restrict__ q,
    const float* __restrict__ k,
    const float* __restrict__ v,
    float* __restrict__ out) {
  __shared__ float ks[ROWS * E_DIM];  // 20 KB

  // XCD-aware swizzle (grid = 512, divisible by 8)
  const int cpx = gridDim.x >> 3;
  const int bid = (blockIdx.x & 7) * cpx + (blockIdx.x >> 3);

  const int tile = bid & (L_DIM / TQ - 1);  // 32 tiles per (b,h)
  const int bh = bid >> 5;
  const int h = bh & (H_DIM - 1);
  const int b = bh >> 3;
  const int l0 = tile * TQ;

  const int tid = threadIdx.x;
  const int wv = tid >> 6;     // wave [0,8)
  const int lane = tid & 63;
  const int qsub = lane >> 3;  // query within wave [0,8)
  const int c = lane & 7;      // channel group [0,8)

  const size_t bhb = (size_t)b * L_DIM * H_DIM + h;

  // ---- stage K only: 20 chunks of 4 rows x 64 floats; wave takes ch%8==wv.
  const int rsub = lane >> 4;
  const int c4 = lane & 15;
#pragma unroll
  for (int t = 0; t < 3; ++t) {
    const int ch = wv + t * 8;
    if (ch < 20) {
      const int rl = ch * 4 + rsub;  // LDS row 0..79
      int rg = l0 - HALO + rl;
      rg = rg < 0 ? 0 : (rg > L_DIM - 1 ? L_DIM - 1 : rg);
      const float4 val =
          *(const float4*)(k + ((bhb + (size_t)rg * H_DIM) << 6) + c4 * 4);
      *(float4*)&ks[(rl * 16 + (c4 ^ (rl & 7))) * 4] = val;
    }
  }

  // ---- Q -> regs (overlaps staging latency) ----
  const int l0w = l0 + wv * 8;
  const int l = l0w + qsub;
  const float* qp = q + ((bhb + (size_t)l * H_DIM) << 6) + c * 8;
  float4 q0 = *(const float4*)qp;
  float4 q1 = *(const float4*)(qp + 4);
  const float scale = 0.125f;  // 1/sqrt(64)
  q0.x *= scale; q0.y *= scale; q0.z *= scale; q0.w *= scale;
  q1.x *= scale; q1.y *= scale; q1.z *= scale; q1.w *= scale;

  __syncthreads();

  // ---- scores: each query group walks its own 15-key band from LDS ----
  // LDS row for band pos j: rl = wv*8 + 1 + qsub + j (in [1,78])
  const int base_rl = wv * 8 + 1 + qsub;
  float sc[NK];
#pragma unroll
  for (int j = 0; j < NK; ++j) {
    const int rl = base_rl + j;
    const int s8 = rl & 7;
    const float4 k0 = *(const float4*)&ks[(rl * 16 + ((2 * c) ^ s8)) * 4];
    const float4 k1 = *(const float4*)&ks[(rl * 16 + ((2 * c + 1) ^ s8)) * 4];
    float s = q0.x * k0.x + q0.y * k0.y + q0.z * k0.z + q0.w * k0.w +
              q1.x * k1.x + q1.y * k1.y + q1.z * k1.z + q1.w * k1.w;
    s = dpp_add<0xB1>(s);   // xor 1 (quad_perm [1,0,3,2])
    s = dpp_add<0x4E>(s);   // xor 2 (quad_perm [2,3,0,1])
    s = dpp_add<0x141>(s);  // 8-lane half-row mirror
    const int kk = l0w + qsub - W + j;
    sc[j] = ((unsigned)kk < (unsigned)L_DIM) ? s : -INFINITY;
  }

  // ---- softmax over 15 band scores ----
  float mx = sc[0];
#pragma unroll
  for (int j = 1; j < NK; ++j) mx = fmaxf(mx, sc[j]);
  float den = 0.0f;
#pragma unroll
  for (int j = 0; j < NK; ++j) {
    sc[j] = __expf(sc[j] - mx);
    den += sc[j];
  }
  const float inv = __builtin_amdgcn_rcpf(den);

  // ---- PV: private-row walk over V, direct from global (L1/L2-hot) ----
  float4 a0 = {0.f, 0.f, 0.f, 0.f};
  float4 a1 = {0.f, 0.f, 0.f, 0.f};
#pragma unroll
  for (int j = 0; j < NK; ++j) {
    int kk = l0w + qsub - W + j;
    kk = kk < 0 ? 0 : (kk > L_DIM - 1 ? L_DIM - 1 : kk);  // p=0 for clamped
    const float* vp = v + ((bhb + (size_t)kk * H_DIM) << 6) + c * 8;
    const float4 v0 = *(const float4*)vp;
    const float4 v1 = *(const float4*)(vp + 4);
    const float p = sc[j];
    a0.x += p * v0.x; a0.y += p * v0.y; a0.z += p * v0.z; a0.w += p * v0.w;
    a1.x += p * v1.x; a1.y += p * v1.y; a1.z += p * v1.z; a1.w += p * v1.w;
  }

  float* op = out + ((bhb + (size_t)l * H_DIM) << 6) + c * 8;
  a0.x *= inv; a0.y *= inv; a0.z *= inv; a0.w *= inv;
  a1.x *= inv; a1.y *= inv; a1.z *= inv; a1.w *= inv;
  *(float4*)op = a0;
  *(float4*)(op + 4) = a1;
}

extern "C" void kernel_launch(void* const* d_in, const int* in_sizes, int n_in,
                              void* d_out, int out_size, void* d_ws, size_t ws_size,
                              hipStream_t stream) {
  const float* q = (const float*)d_in[0];
  const float* k = (const float*)d_in[1];
  const float* v = (const float*)d_in[2];
  float* out = (float*)d_out;

  const int B = in_sizes[0] / (L_DIM * H_DIM * E_DIM);  // = 2
  const int blocks = B * H_DIM * (L_DIM / TQ);          // 512

  local_attn_kernel<<<blocks, 512, 0, stream>>>(q, k, v, out);
}

// Round 8
// 12.203 us; speedup vs baseline: 1.4508x; 1.0884x over previous
//
#include <hip/hip_runtime.h>
#include <math.h>

// Local banded attention: B=2, L=2048, H=8, E=D=64, window w=7 (band=15).
// R7: 16 lanes per query (lane owns 4 channels = 1 float4) -> 8192 waves
// total = 8 waves/SIMD resident (2x R3's occupancy; kernel is latency-bound).
// Block = 512 threads (8 waves) = 32 queries of one (b,h); K+V staged to
// XOR-swizzled LDS (24KB), single __syncthreads.  Per query group of 16
// lanes: private 15-row band walk, 1 ds_read_b128 per row per matrix.
// Dot reduce = 4 DPP adds (xor1, xor2, half-mirror=xor4, row-mirror=xor8).

constexpr int L_DIM = 2048;
constexpr int H_DIM = 8;
constexpr int E_DIM = 64;
constexpr int W = 7;
constexpr int NK = 2 * W + 1;        // 15 band positions per query
constexpr int TQ = 32;               // queries per block
constexpr int HALO = 8;
constexpr int ROWS = TQ + 2 * HALO;  // 48 staged rows per matrix
constexpr int NCH = ROWS / 4;        // 12 chunks (4 rows x 1KB) per matrix

template <int CTRL>
__device__ __forceinline__ float dpp_add(float s) {
  int t = __builtin_amdgcn_mov_dpp(__builtin_bit_cast(int, s), CTRL, 0xF, 0xF, true);
  return s + __builtin_bit_cast(float, t);
}

__global__ __launch_bounds__(512, 8) void local_attn_kernel(
    const float* __restrict__ q,
    const float* __restrict__ k,
    const float* __restrict__ v,
    float* __restrict__ out) {
  __shared__ float ks[ROWS * E_DIM];  // 12 KB
  __shared__ float vs[ROWS * E_DIM];  // 12 KB

  // XCD-aware swizzle (grid = 1024, divisible by 8)
  const int cpx = gridDim.x >> 3;
  const int bid = (blockIdx.x & 7) * cpx + (blockIdx.x >> 3);

  const int tile = bid & (L_DIM / TQ - 1);  // 64 tiles per (b,h)
  const int bh = bid >> 6;
  const int h = bh & (H_DIM - 1);
  const int b = bh >> 3;
  const int l0 = tile * TQ;

  const int tid = threadIdx.x;
  const int wv = tid >> 6;     // wave [0,8)
  const int lane = tid & 63;
  const int qsub = lane >> 4;  // query within wave [0,4)
  const int c4 = lane & 15;    // 16B column group [0,16) -> channels c4*4..+3

  const size_t bhb = (size_t)b * L_DIM * H_DIM + h;

  // ---- stage K and V: 24 chunks of 4 rows x 64 floats; wave takes 3 ----
  const int rsub = lane >> 4;  // row within chunk (== qsub)
#pragma unroll
  for (int t = 0; t < 3; ++t) {
    const int ch = wv + t * 8;               // 0..23
    const int m = (ch >= NCH) ? 1 : 0;       // 0: K, 1: V
    const int cc = ch - m * NCH;
    const int rl = cc * 4 + rsub;            // LDS row 0..47
    int rg = l0 - HALO + rl;
    rg = rg < 0 ? 0 : (rg > L_DIM - 1 ? L_DIM - 1 : rg);
    const float4 val =
        *(const float4*)((m ? v : k) + ((bhb + (size_t)rg * H_DIM) << 6) + c4 * 4);
    *(float4*)&((m ? vs : ks)[(rl * 16 + (c4 ^ (rl & 7))) * 4]) = val;
  }

  // ---- Q -> regs (one float4 per lane; overlaps staging) ----
  const int l0w = l0 + wv * 4;
  const int l = l0w + qsub;
  float4 q0 = *(const float4*)(q + ((bhb + (size_t)l * H_DIM) << 6) + c4 * 4);
  const float scale = 0.125f;  // 1/sqrt(64)
  q0.x *= scale; q0.y *= scale; q0.z *= scale; q0.w *= scale;

  __syncthreads();

  // ---- scores: each 16-lane query group walks its own 15-key band ----
  // LDS row for band pos j: rl = wv*4 + 1 + qsub + j (in [1,46])
  const int base_rl = wv * 4 + 1 + qsub;
  float sc[NK];
#pragma unroll
  for (int j = 0; j < NK; ++j) {
    const int rl = base_rl + j;
    const float4 k0 = *(const float4*)&ks[(rl * 16 + (c4 ^ (rl & 7))) * 4];
    float s = q0.x * k0.x + q0.y * k0.y + q0.z * k0.z + q0.w * k0.w;
    s = dpp_add<0xB1>(s);   // xor 1 (quad_perm [1,0,3,2])
    s = dpp_add<0x4E>(s);   // xor 2 (quad_perm [2,3,0,1])
    s = dpp_add<0x141>(s);  // half-row mirror == xor 4 (quads uniform)
    s = dpp_add<0x140>(s);  // row mirror == xor 8 (octets uniform)
    const int kk = l0w + qsub - W + j;
    sc[j] = ((unsigned)kk < (unsigned)L_DIM) ? s : -INFINITY;
  }

  // ---- softmax over 15 band scores (identical across the 16 lanes) ----
  float mx = sc[0];
#pragma unroll
  for (int j = 1; j < NK; ++j) mx = fmaxf(mx, sc[j]);
  float den = 0.0f;
#pragma unroll
  for (int j = 0; j < NK; ++j) {
    sc[j] = __expf(sc[j] - mx);
    den += sc[j];
  }
  const float inv = __builtin_amdgcn_rcpf(den);

  // ---- PV: private-row walk over V ----
  float4 a0 = {0.f, 0.f, 0.f, 0.f};
#pragma unroll
  for (int j = 0; j < NK; ++j) {
    const int rl = base_rl + j;
    const float4 v0 = *(const float4*)&vs[(rl * 16 + (c4 ^ (rl & 7))) * 4];
    const float p = sc[j];
    a0.x += p * v0.x; a0.y += p * v0.y; a0.z += p * v0.z; a0.w += p * v0.w;
  }

  float* op = out + ((bhb + (size_t)l * H_DIM) << 6) + c4 * 4;
  a0.x *= inv; a0.y *= inv; a0.z *= inv; a0.w *= inv;
  *(float4*)op = a0;
}

extern "C" void kernel_launch(void* const* d_in, const int* in_sizes, int n_in,
                              void* d_out, int out_size, void* d_ws, size_t ws_size,
                              hipStream_t stream) {
  const float* q = (const float*)d_in[0];
  const float* k = (const float*)d_in[1];
  const float* v = (const float*)d_in[2];
  float* out = (float*)d_out;

  const int B = in_sizes[0] / (L_DIM * H_DIM * E_DIM);  // = 2
  const int blocks = B * H_DIM * (L_DIM / TQ);          // 1024

  local_attn_kernel<<<blocks, 512, 0, stream>>>(q, k, v, out);
}